// Round 1
// baseline (5861.795 us; speedup 1.0000x reference)
//
#include <hip/hip_runtime.h>
#include <hip/hip_cooperative_groups.h>

namespace cg = cooperative_groups;

#define BB   64
#define LL   32
#define TT   31
#define VV   16000
#define PP   256
#define CE   512   // ENC
#define CD   512   // DEC
#define CA   512   // ATT
#define CEMB 256
#define G4   2048  // 4*DEC

typedef unsigned short u16;

struct alignas(16) u16x8 { u16 v[8]; };

__device__ __forceinline__ float bf2f(u16 u){
  union { unsigned int i; float f; } x; x.i = ((unsigned int)u) << 16; return x.f;
}
__device__ __forceinline__ u16 f2bf(float f){
  union { float f; unsigned int i; } x; x.f = f;
  unsigned int r = x.i + 0x7fffu + ((x.i >> 16) & 1u);
  return (u16)(r >> 16);
}
__device__ __forceinline__ float sigm(float x){ return 1.0f/(1.0f + __expf(-x)); }

// detect int64-vs-int32 integer inputs (lens sorted desc, lens[1] in [2,32] != 0;
// int64 little-endian puts a 0 high-word at 32-bit slot 1).
__global__ void k_detect(const int* __restrict__ lens32, int* __restrict__ flag){
  if (threadIdx.x == 0 && blockIdx.x == 0) flag[0] = (lens32[1] == 0) ? 1 : 0;
}

// ---------------- one-time prep ----------------

__global__ __launch_bounds__(256) void k_mean(const float* __restrict__ eo,
                                              float* __restrict__ mean_enc){
  int i = blockIdx.x*256 + threadIdx.x;            // b*CE + c  (32768 total)
  const float4* row = (const float4*)(eo + (size_t)i*PP);
  float s = 0.f;
  for (int j = 0; j < PP/4; j++){
    float4 w = row[j];
    s += w.x + w.y + w.z + w.w;
  }
  mean_enc[i] = s * (1.0f/PP);
}

__global__ __launch_bounds__(256) void k_init(const float* __restrict__ mean_enc,
    const float* __restrict__ Wh, const float* __restrict__ bh,
    const float* __restrict__ Wc, const float* __restrict__ bc,
    float* __restrict__ h, float* __restrict__ c){
  __shared__ float ms[CE];
  int b = blockIdx.x >> 1, half = blockIdx.x & 1;
  int tid = threadIdx.x;
  ms[tid]       = mean_enc[b*CE + tid];
  ms[tid + 256] = mean_enc[b*CE + 256 + tid];
  __syncthreads();
  int d = half*256 + tid;
  const float4* wh = (const float4*)(Wh + (size_t)d*CE);
  const float4* wc = (const float4*)(Wc + (size_t)d*CE);
  float ah = 0.f, ac = 0.f;
  for (int k4 = 0; k4 < CE/4; k4++){
    float4 a = wh[k4], bq = wc[k4];
    float m0 = ms[k4*4+0], m1 = ms[k4*4+1], m2 = ms[k4*4+2], m3 = ms[k4*4+3];
    ah = fmaf(m0,a.x, fmaf(m1,a.y, fmaf(m2,a.z, fmaf(m3,a.w, ah))));
    ac = fmaf(m0,bq.x,fmaf(m1,bq.y,fmaf(m2,bq.z,fmaf(m3,bq.w, ac))));
  }
  h[b*CD + d] = ah + bh[d];
  c[b*CD + d] = ac + bc[d];
}

__global__ __launch_bounds__(256) void k_emb(const int* __restrict__ caps,
                                             const float* __restrict__ emb,
                                             float* __restrict__ eseq,
                                             const int* __restrict__ flag){
  int i = blockIdx.x*256 + threadIdx.x;            // 4-element groups
  if (i >= BB*TT*CEMB/4) return;
  int flat = i*4;
  int b = flat / (TT*CEMB);
  int r = flat % (TT*CEMB);
  int t = r / CEMB;
  int e = r % CEMB;
  int li = b*LL + t;
  int tok = flag[0] ? caps[2*li] : caps[li];
  tok = tok < 0 ? 0 : (tok >= VV ? VV-1 : tok);   // OOB insurance
  *(float4*)(eseq + flat) = *(const float4*)(emb + (size_t)tok*CEMB + e);
}

// att1[b][p][a] = sum_c enc[b][p][c]*Wea[a][c] + bea[a], stored bf16 in scratch.
__global__ __launch_bounds__(256) void k_att1(const float* __restrict__ eo,
    const float* __restrict__ W, const float* __restrict__ bias,
    u16* __restrict__ att1){
  __shared__ float As[16][132];
  __shared__ float Bs[16][132];
  int b  = blockIdx.z;
  int p0 = blockIdx.y * 128;
  int a0 = blockIdx.x * 128;
  int tid = threadIdx.x;
  int ty = tid >> 4, tx = tid & 15;
  float acc[8][8] = {};
  int lk  = tid >> 4;
  int lm  = (tid & 15) * 8;
  int ln  = tid >> 1;
  int lkb = (tid & 1) * 8;
  for (int c0 = 0; c0 < CE; c0 += 16){
    __syncthreads();
    const float* ap = eo + ((size_t)b*CE + c0 + lk)*PP + p0 + lm;
    float4 av0 = *(const float4*)ap;
    float4 av1 = *(const float4*)(ap + 4);
    As[lk][lm+0]=av0.x; As[lk][lm+1]=av0.y; As[lk][lm+2]=av0.z; As[lk][lm+3]=av0.w;
    As[lk][lm+4]=av1.x; As[lk][lm+5]=av1.y; As[lk][lm+6]=av1.z; As[lk][lm+7]=av1.w;
    const float* bp = W + (size_t)(a0 + ln)*CE + c0 + lkb;
    float4 bw0 = *(const float4*)bp;
    float4 bw1 = *(const float4*)(bp + 4);
    Bs[lkb+0][ln]=bw0.x; Bs[lkb+1][ln]=bw0.y; Bs[lkb+2][ln]=bw0.z; Bs[lkb+3][ln]=bw0.w;
    Bs[lkb+4][ln]=bw1.x; Bs[lkb+5][ln]=bw1.y; Bs[lkb+6][ln]=bw1.z; Bs[lkb+7][ln]=bw1.w;
    __syncthreads();
    #pragma unroll
    for (int k = 0; k < 16; k++){
      float4 a0v = *(const float4*)&As[k][ty*8];
      float4 a1v = *(const float4*)&As[k][ty*8 + 4];
      float4 b0v = *(const float4*)&Bs[k][tx*8];
      float4 b1v = *(const float4*)&Bs[k][tx*8 + 4];
      float a[8]  = {a0v.x,a0v.y,a0v.z,a0v.w,a1v.x,a1v.y,a1v.z,a1v.w};
      float bb[8] = {b0v.x,b0v.y,b0v.z,b0v.w,b1v.x,b1v.y,b1v.z,b1v.w};
      #pragma unroll
      for (int i2 = 0; i2 < 8; i2++)
        #pragma unroll
        for (int j2 = 0; j2 < 8; j2++)
          acc[i2][j2] = fmaf(a[i2], bb[j2], acc[i2][j2]);
    }
  }
  float bv[8];
  #pragma unroll
  for (int j2 = 0; j2 < 8; j2++) bv[j2] = bias[a0 + tx*8 + j2];
  #pragma unroll
  for (int i2 = 0; i2 < 8; i2++){
    int p = p0 + ty*8 + i2;
    u16x8 o;
    #pragma unroll
    for (int j2 = 0; j2 < 8; j2++) o.v[j2] = f2bf(acc[i2][j2] + bv[j2]);
    *(u16x8*)(att1 + ((size_t)(b*PP + p))*CA + a0 + tx*8) = o;
  }
}

// ---------------- persistent recurrent loop (cooperative) ----------------

struct AttSh  { float hs[CD], att2s[CA], gs[CE], wl[CA], es[PP], red[8]; };
struct GatesSh{ float As[16][68], Bs[16][68]; };
union SharedU { AttSh att; GatesSh g; };

__device__ __forceinline__ void att_body(int b, int tid, SharedU& S,
    const float* __restrict__ h,
    const float* __restrict__ Wd, const float* __restrict__ bd,
    const float* __restrict__ Wb, const float* __restrict__ bb_,
    const float* __restrict__ wfull, const float* __restrict__ bfull,
    const u16* __restrict__ att1, const float* __restrict__ eo,
    float* __restrict__ awe){
  float* hs    = S.att.hs;
  float* att2s = S.att.att2s;
  float* gs    = S.att.gs;
  float* wl    = S.att.wl;
  float* es    = S.att.es;
  float* red   = S.att.red;
  hs[tid]       = h[b*CD + tid];
  hs[tid + 256] = h[b*CD + 256 + tid];
  wl[tid]       = wfull[tid];
  wl[tid + 256] = wfull[256 + tid];
  __syncthreads();
  {
    const float4* r0 = (const float4*)(Wd + (size_t)tid*CD);
    const float4* r1 = (const float4*)(Wd + (size_t)(tid + 256)*CD);
    const float4* r2 = (const float4*)(Wb + (size_t)tid*CD);
    const float4* r3 = (const float4*)(Wb + (size_t)(tid + 256)*CD);
    float a0 = 0.f, a1 = 0.f, a2 = 0.f, a3 = 0.f;
    for (int k4 = 0; k4 < CD/4; k4++){
      float4 w0 = r0[k4], w1 = r1[k4], w2 = r2[k4], w3 = r3[k4];
      float h0 = hs[k4*4+0], h1 = hs[k4*4+1], h2 = hs[k4*4+2], h3 = hs[k4*4+3];
      a0 = fmaf(h0,w0.x, fmaf(h1,w0.y, fmaf(h2,w0.z, fmaf(h3,w0.w, a0))));
      a1 = fmaf(h0,w1.x, fmaf(h1,w1.y, fmaf(h2,w1.z, fmaf(h3,w1.w, a1))));
      a2 = fmaf(h0,w2.x, fmaf(h1,w2.y, fmaf(h2,w2.z, fmaf(h3,w2.w, a2))));
      a3 = fmaf(h0,w3.x, fmaf(h1,w3.y, fmaf(h2,w3.z, fmaf(h3,w3.w, a3))));
    }
    att2s[tid]       = a0 + bd[tid];
    att2s[tid + 256] = a1 + bd[tid + 256];
    gs[tid]          = sigm(a2 + bb_[tid]);
    gs[tid + 256]    = sigm(a3 + bb_[tid + 256]);
  }
  __syncthreads();
  float e;
  {
    const u16x8* ar = (const u16x8*)(att1 + ((size_t)(b*PP + tid))*CA);
    float s = 0.f;
    for (int k8 = 0; k8 < CA/8; k8++){
      u16x8 a8 = ar[k8];
      #pragma unroll
      for (int q = 0; q < 8; q++){
        float v = bf2f(a8.v[q]) + att2s[k8*8 + q];
        s = fmaf(fmaxf(v, 0.f), wl[k8*8 + q], s);
      }
    }
    e = s + bfull[0];
  }
  int lane = tid & 63, wid = tid >> 6;
  float v = e;
  #pragma unroll
  for (int off = 32; off; off >>= 1) v = fmaxf(v, __shfl_xor(v, off, 64));
  if (lane == 0) red[wid] = v;
  __syncthreads();
  float mx = fmaxf(fmaxf(red[0], red[1]), fmaxf(red[2], red[3]));
  float ex = __expf(e - mx);
  float sm = ex;
  #pragma unroll
  for (int off = 32; off; off >>= 1) sm += __shfl_xor(sm, off, 64);
  if (lane == 0) red[4 + wid] = sm;
  __syncthreads();
  float tot = red[4] + red[5] + red[6] + red[7];
  es[tid] = ex / tot;
  __syncthreads();
  {
    const float4* e0 = (const float4*)(eo + ((size_t)b*CE + tid)*PP);
    const float4* e1 = (const float4*)(eo + ((size_t)b*CE + tid + 256)*PP);
    float s0 = 0.f, s1 = 0.f;
    for (int p4 = 0; p4 < PP/4; p4++){
      float4 q0 = e0[p4], q1 = e1[p4];
      float l0 = es[p4*4+0], l1 = es[p4*4+1], l2 = es[p4*4+2], l3 = es[p4*4+3];
      s0 = fmaf(q0.x,l0, fmaf(q0.y,l1, fmaf(q0.z,l2, fmaf(q0.w,l3, s0))));
      s1 = fmaf(q1.x,l0, fmaf(q1.y,l1, fmaf(q1.z,l2, fmaf(q1.w,l3, s1))));
    }
    awe[b*CE + tid]       = s0 * gs[tid];
    awe[b*CE + tid + 256] = s1 * gs[tid + 256];
  }
}

__device__ __forceinline__ void gates_body(int chunk, int jblk, int tid, SharedU& S,
    const float* __restrict__ eseq, const float* __restrict__ awe,
    const float* __restrict__ h,
    const float* __restrict__ Wih, const float* __restrict__ Whh,
    float* __restrict__ gslab, int t){
  int j0 = jblk * 64;
  int ty = tid >> 4, tx = tid & 15;
  const float* Wbase; int wrow, wcol0;
  if (chunk < 3){ Wbase = Wih; wrow = 768; wcol0 = chunk * 256; }
  else          { Wbase = Whh; wrow = 512; wcol0 = (chunk - 3) * 256; }
  float acc[4][4] = {};
  int lb  = tid >> 2;
  int lk4 = (tid & 3) * 4;
  int ln  = tid >> 2;
  int lkb = (tid & 3) * 4;
  for (int k0 = 0; k0 < 256; k0 += 16){
    __syncthreads();
    const float* src;
    if (chunk == 0)      src = eseq + ((size_t)lb*TT + t)*CEMB;
    else if (chunk < 3)  src = awe + lb*CE + (chunk - 1)*256;
    else                 src = h   + lb*CD + (chunk - 3)*256;
    float4 q = *(const float4*)(src + k0 + lk4);
    S.g.As[lk4+0][lb] = q.x; S.g.As[lk4+1][lb] = q.y;
    S.g.As[lk4+2][lb] = q.z; S.g.As[lk4+3][lb] = q.w;
    float4 w4 = *(const float4*)(Wbase + (size_t)(j0 + ln)*wrow + wcol0 + k0 + lkb);
    S.g.Bs[lkb+0][ln] = w4.x; S.g.Bs[lkb+1][ln] = w4.y;
    S.g.Bs[lkb+2][ln] = w4.z; S.g.Bs[lkb+3][ln] = w4.w;
    __syncthreads();
    #pragma unroll
    for (int k = 0; k < 16; k++){
      float4 av = *(const float4*)&S.g.As[k][ty*4];
      float4 bv = *(const float4*)&S.g.Bs[k][tx*4];
      float a[4] = {av.x, av.y, av.z, av.w};
      float bq[4] = {bv.x, bv.y, bv.z, bv.w};
      #pragma unroll
      for (int i2 = 0; i2 < 4; i2++)
        #pragma unroll
        for (int j2 = 0; j2 < 4; j2++)
          acc[i2][j2] = fmaf(a[i2], bq[j2], acc[i2][j2]);
    }
  }
  #pragma unroll
  for (int i2 = 0; i2 < 4; i2++){
    int bq = ty*4 + i2;
    float4 o = make_float4(acc[i2][0], acc[i2][1], acc[i2][2], acc[i2][3]);
    *(float4*)(gslab + ((size_t)chunk*BB + bq)*G4 + j0 + tx*4) = o;
  }
}

__device__ __forceinline__ void lstm_body(int blk, int tid,
    const float* __restrict__ gslab,
    const float* __restrict__ bih, const float* __restrict__ bhh,
    float* __restrict__ h, float* __restrict__ c,
    float* __restrict__ h_all, int t){
  int i = blk*256 + tid;   // 32768
  int b = i >> 9, d = i & 511;
  float gi = bih[d]        + bhh[d];
  float gf = bih[d + 512]  + bhh[d + 512];
  float gg = bih[d + 1024] + bhh[d + 1024];
  float go = bih[d + 1536] + bhh[d + 1536];
  #pragma unroll
  for (int s = 0; s < 5; s++){
    const float* base = gslab + ((size_t)s*BB + b)*G4;
    gi += base[d]; gf += base[d + 512]; gg += base[d + 1024]; go += base[d + 1536];
  }
  float cn = sigm(gf)*c[i] + sigm(gi)*tanhf(gg);
  float hn = sigm(go)*tanhf(cn);
  c[i] = cn; h[i] = hn;
  h_all[((size_t)b*TT + t)*CD + d] = hn;
}

// phase A: blocks 0..63 attention (b=blk); blocks 64..159 gates chunks {0,3,4}
// phase B: blocks 0..63 gates chunks {1,2}
// phase C: blocks 0..127 lstm pointwise
__global__ __launch_bounds__(256) void k_loop(
    const float* __restrict__ eo, const u16* __restrict__ att1,
    const float* __restrict__ eseq,
    const float* __restrict__ Wda, const float* __restrict__ bda,
    const float* __restrict__ Wbe, const float* __restrict__ bbe,
    const float* __restrict__ wfull, const float* __restrict__ bfull,
    const float* __restrict__ Wih, const float* __restrict__ Whh,
    const float* __restrict__ bih, const float* __restrict__ bhh,
    float* __restrict__ hbuf, float* __restrict__ cbuf,
    float* __restrict__ awe, float* __restrict__ gslab,
    float* __restrict__ h_all){
  cg::grid_group grid = cg::this_grid();
  __shared__ SharedU S;
  int blk = blockIdx.x, tid = threadIdx.x;
  for (int t = 0; t < TT; t++){
    if (blk < 64){
      att_body(blk, tid, S, hbuf, Wda, bda, Wbe, bbe, wfull, bfull, att1, eo, awe);
    } else {
      int local = blk - 64;                         // 0..95
      int chunk = (local < 32) ? 0 : ((local < 64) ? 3 : 4);
      gates_body(chunk, local & 31, tid, S, eseq, awe, hbuf, Wih, Whh, gslab, t);
    }
    grid.sync();
    if (blk < 64){
      gates_body(1 + (blk >> 5), blk & 31, tid, S, eseq, awe, hbuf, Wih, Whh, gslab, t);
    }
    grid.sync();
    if (blk < 128){
      lstm_body(blk, tid, gslab, bih, bhh, hbuf, cbuf, h_all, t);
    }
    grid.sync();
  }
}

// ---------------- final big GEMM, fp32 output ----------------
__global__ __launch_bounds__(256) void k_pred(
    const float* __restrict__ h_all, const float* __restrict__ Wfc,
    const float* __restrict__ bfc, const int* __restrict__ lens,
    const int* __restrict__ flag, float* __restrict__ out){
  __shared__ float As[16][132];
  __shared__ float Bs[16][132];
  int n0 = blockIdx.x * 128;
  int m0 = blockIdx.y * 128;
  int tid = threadIdx.x;
  int ty = tid >> 4, tx = tid & 15;
  float acc[8][8] = {};
  int lm  = tid >> 1;
  int lkb = (tid & 1) * 8;
  for (int c0 = 0; c0 < CD; c0 += 16){
    __syncthreads();
    int m = m0 + lm;
    float4 a0v, a1v;
    if (m < BB*TT){
      a0v = *(const float4*)(h_all + (size_t)m*CD + c0 + lkb);
      a1v = *(const float4*)(h_all + (size_t)m*CD + c0 + lkb + 4);
    } else {
      a0v = make_float4(0.f,0.f,0.f,0.f); a1v = a0v;
    }
    As[lkb+0][lm] = a0v.x; As[lkb+1][lm] = a0v.y; As[lkb+2][lm] = a0v.z; As[lkb+3][lm] = a0v.w;
    As[lkb+4][lm] = a1v.x; As[lkb+5][lm] = a1v.y; As[lkb+6][lm] = a1v.z; As[lkb+7][lm] = a1v.w;
    const float* bp = Wfc + (size_t)(n0 + lm)*CD + c0 + lkb;
    float4 b0v = *(const float4*)bp;
    float4 b1v = *(const float4*)(bp + 4);
    Bs[lkb+0][lm] = b0v.x; Bs[lkb+1][lm] = b0v.y; Bs[lkb+2][lm] = b0v.z; Bs[lkb+3][lm] = b0v.w;
    Bs[lkb+4][lm] = b1v.x; Bs[lkb+5][lm] = b1v.y; Bs[lkb+6][lm] = b1v.z; Bs[lkb+7][lm] = b1v.w;
    __syncthreads();
    #pragma unroll
    for (int k = 0; k < 16; k++){
      float4 av0 = *(const float4*)&As[k][ty*8];
      float4 av1 = *(const float4*)&As[k][ty*8 + 4];
      float4 bv0 = *(const float4*)&Bs[k][tx*8];
      float4 bv1 = *(const float4*)&Bs[k][tx*8 + 4];
      float a[8]  = {av0.x,av0.y,av0.z,av0.w,av1.x,av1.y,av1.z,av1.w};
      float bb[8] = {bv0.x,bv0.y,bv0.z,bv0.w,bv1.x,bv1.y,bv1.z,bv1.w};
      #pragma unroll
      for (int i2 = 0; i2 < 8; i2++)
        #pragma unroll
        for (int j2 = 0; j2 < 8; j2++)
          acc[i2][j2] = fmaf(a[i2], bb[j2], acc[i2][j2]);
    }
  }
  float bv[8];
  #pragma unroll
  for (int j2 = 0; j2 < 8; j2++) bv[j2] = bfc[n0 + tx*8 + j2];
  int f = flag[0];
  #pragma unroll
  for (int i2 = 0; i2 < 8; i2++){
    int m = m0 + ty*8 + i2;
    if (m < BB*TT){
      int b = m / TT, t = m - b*TT;
      int lb = f ? lens[2*b] : lens[b];
      bool active = (t < lb - 1);
      float4 o0, o1;
      if (active){
        o0 = make_float4(acc[i2][0]+bv[0], acc[i2][1]+bv[1], acc[i2][2]+bv[2], acc[i2][3]+bv[3]);
        o1 = make_float4(acc[i2][4]+bv[4], acc[i2][5]+bv[5], acc[i2][6]+bv[6], acc[i2][7]+bv[7]);
      } else {
        o0 = make_float4(0.f,0.f,0.f,0.f); o1 = o0;
      }
      float* op = out + (size_t)m*VV + n0 + tx*8;
      *(float4*)op       = o0;
      *(float4*)(op + 4) = o1;
    }
  }
}

extern "C" void kernel_launch(void* const* d_in, const int* in_sizes, int n_in,
                              void* d_out, int out_size, void* d_ws, size_t ws_size,
                              hipStream_t stream){
  const float* eo    = (const float*)d_in[0];
  const int*   caps  = (const int*)d_in[1];
  const int*   lens  = (const int*)d_in[2];
  const float* Wea   = (const float*)d_in[3];
  const float* bea   = (const float*)d_in[4];
  const float* Wda   = (const float*)d_in[5];
  const float* bda   = (const float*)d_in[6];
  const float* wfull = (const float*)d_in[7];
  const float* bfull = (const float*)d_in[8];
  const float* emb   = (const float*)d_in[9];
  const float* Wih   = (const float*)d_in[10];
  const float* Whh   = (const float*)d_in[11];
  const float* bih   = (const float*)d_in[12];
  const float* bhh   = (const float*)d_in[13];
  const float* Wirh  = (const float*)d_in[14];
  const float* birh  = (const float*)d_in[15];
  const float* Wirc  = (const float*)d_in[16];
  const float* birc  = (const float*)d_in[17];
  const float* Wbe   = (const float*)d_in[18];
  const float* bbe   = (const float*)d_in[19];
  const float* Wfc   = (const float*)d_in[20];
  const float* bfc   = (const float*)d_in[21];
  float* out = (float*)d_out;

  // scratch that dies before k_pred lives in the head of d_out (127 MB fp32);
  // k_pred overwrites every byte of d_out afterwards (stream-ordered).
  char* ob = (char*)d_out;
  u16*   att1     = (u16*)(ob + 0);           // 16,777,216 B
  float* gslab    = (float*)(ob + 16777216);  //  2,621,440 B
  float* eseq     = (float*)(ob + 19398656);  //  2,031,616 B
  float* mean_enc = (float*)(ob + 21430272);  //    131,072 B
  float* awe      = (float*)(ob + 21561344);  //    131,072 B
  float* hbuf     = (float*)(ob + 21692416);  //    131,072 B
  float* cbuf     = (float*)(ob + 21823488);  //    131,072 B  (end 21.95 MB << 127 MB)
  char* w = (char*)d_ws;
  float* h_all    = (float*)w;                //  4,063,232 B
  int*   iflag    = (int*)(w + 4063232);

  k_detect<<<1, 64, 0, stream>>>(lens, iflag);
  k_mean<<<128, 256, 0, stream>>>(eo, mean_enc);
  k_emb <<<496, 256, 0, stream>>>(caps, emb, eseq, iflag);
  k_init<<<128, 256, 0, stream>>>(mean_enc, Wirh, birh, Wirc, birc, hbuf, cbuf);
  k_att1<<<dim3(4, 2, BB), 256, 0, stream>>>(eo, Wea, bea, att1);

  {
    void* kargs[] = {
      (void*)&eo, (void*)&att1, (void*)&eseq,
      (void*)&Wda, (void*)&bda, (void*)&Wbe, (void*)&bbe,
      (void*)&wfull, (void*)&bfull, (void*)&Wih, (void*)&Whh,
      (void*)&bih, (void*)&bhh,
      (void*)&hbuf, (void*)&cbuf, (void*)&awe, (void*)&gslab, (void*)&h_all
    };
    hipLaunchCooperativeKernel(reinterpret_cast<void*>(k_loop),
                               dim3(160), dim3(256), kargs, 0, stream);
  }

  k_pred<<<dim3(125, 16), 256, 0, stream>>>(h_all, Wfc, bfc, lens, iflag, out);
}

// Round 2
// 3226.715 us; speedup vs baseline: 1.8166x; 1.8166x over previous
//
#include <hip/hip_runtime.h>

#define BB   64
#define LL   32
#define TT   31
#define VV   16000
#define PP   256
#define CE   512   // ENC
#define CD   512   // DEC
#define CA   512   // ATT
#define CEMB 256
#define G4   2048  // 4*DEC

typedef unsigned short u16;

struct alignas(16) u16x8 { u16 v[8]; };

__device__ __forceinline__ float bf2f(u16 u){
  union { unsigned int i; float f; } x; x.i = ((unsigned int)u) << 16; return x.f;
}
__device__ __forceinline__ u16 f2bf(float f){
  union { float f; unsigned int i; } x; x.f = f;
  unsigned int r = x.i + 0x7fffu + ((x.i >> 16) & 1u);
  return (u16)(r >> 16);
}
__device__ __forceinline__ float sigm(float x){ return 1.0f/(1.0f + __expf(-x)); }

// detect int64-vs-int32 integer inputs
__global__ void k_detect(const int* __restrict__ lens32, int* __restrict__ flag){
  if (threadIdx.x == 0 && blockIdx.x == 0) flag[0] = (lens32[1] == 0) ? 1 : 0;
}

// ---------------- one-time prep ----------------

__global__ __launch_bounds__(256) void k_mean(const float* __restrict__ eo,
                                              float* __restrict__ mean_enc){
  int i = blockIdx.x*256 + threadIdx.x;            // b*CE + c  (32768 total)
  const float4* row = (const float4*)(eo + (size_t)i*PP);
  float s = 0.f;
  for (int j = 0; j < PP/4; j++){
    float4 w = row[j];
    s += w.x + w.y + w.z + w.w;
  }
  mean_enc[i] = s * (1.0f/PP);
}

// eoT[b][p][c] = eo[b][c][p]  (coalesced transpose for the awe reduction)
__global__ __launch_bounds__(256) void k_trans(const float* __restrict__ eo,
                                               float* __restrict__ eoT){
  __shared__ float T[64][65];
  int b = blockIdx.z, c0 = blockIdx.x*64, p0 = blockIdx.y*64;
  int tid = threadIdx.x;
  int lx = tid & 63, ly = tid >> 6;                // ly 0..3
  #pragma unroll
  for (int r = 0; r < 16; r++){
    int c = ly + 4*r;
    T[c][lx] = eo[((size_t)b*CE + c0 + c)*PP + p0 + lx];
  }
  __syncthreads();
  #pragma unroll
  for (int r = 0; r < 16; r++){
    int p = ly + 4*r;
    eoT[((size_t)b*PP + p0 + p)*CE + c0 + lx] = T[lx][p];
  }
}

__global__ __launch_bounds__(256) void k_init(const float* __restrict__ mean_enc,
    const float* __restrict__ Wh, const float* __restrict__ bh,
    const float* __restrict__ Wc, const float* __restrict__ bc,
    float* __restrict__ h, float* __restrict__ c){
  __shared__ float ms[CE];
  int b = blockIdx.x >> 1, half = blockIdx.x & 1;
  int tid = threadIdx.x;
  ms[tid]       = mean_enc[b*CE + tid];
  ms[tid + 256] = mean_enc[b*CE + 256 + tid];
  __syncthreads();
  int d = half*256 + tid;
  const float4* wh = (const float4*)(Wh + (size_t)d*CE);
  const float4* wc = (const float4*)(Wc + (size_t)d*CE);
  float ah = 0.f, ac = 0.f;
  for (int k4 = 0; k4 < CE/4; k4++){
    float4 a = wh[k4], bq = wc[k4];
    float m0 = ms[k4*4+0], m1 = ms[k4*4+1], m2 = ms[k4*4+2], m3 = ms[k4*4+3];
    ah = fmaf(m0,a.x, fmaf(m1,a.y, fmaf(m2,a.z, fmaf(m3,a.w, ah))));
    ac = fmaf(m0,bq.x,fmaf(m1,bq.y,fmaf(m2,bq.z,fmaf(m3,bq.w, ac))));
  }
  h[b*CD + d] = ah + bh[d];
  c[b*CD + d] = ac + bc[d];
}

__global__ __launch_bounds__(256) void k_emb(const int* __restrict__ caps,
                                             const float* __restrict__ emb,
                                             float* __restrict__ eseq,
                                             const int* __restrict__ flag){
  int i = blockIdx.x*256 + threadIdx.x;            // 4-element groups
  if (i >= BB*TT*CEMB/4) return;
  int flat = i*4;
  int b = flat / (TT*CEMB);
  int r = flat % (TT*CEMB);
  int t = r / CEMB;
  int e = r % CEMB;
  int li = b*LL + t;
  int tok = flag[0] ? caps[2*li] : caps[li];
  tok = tok < 0 ? 0 : (tok >= VV ? VV-1 : tok);
  *(float4*)(eseq + flat) = *(const float4*)(emb + (size_t)tok*CEMB + e);
}

// att1[b][p][a] = sum_c enc[b][p][c]*Wea[a][c] + bea[a], stored bf16 in scratch.
__global__ __launch_bounds__(256) void k_att1(const float* __restrict__ eo,
    const float* __restrict__ W, const float* __restrict__ bias,
    u16* __restrict__ att1){
  __shared__ float As[16][132];
  __shared__ float Bs[16][132];
  int b  = blockIdx.z;
  int p0 = blockIdx.y * 128;
  int a0 = blockIdx.x * 128;
  int tid = threadIdx.x;
  int ty = tid >> 4, tx = tid & 15;
  float acc[8][8] = {};
  int lk  = tid >> 4;
  int lm  = (tid & 15) * 8;
  int ln  = tid >> 1;
  int lkb = (tid & 1) * 8;
  for (int c0 = 0; c0 < CE; c0 += 16){
    __syncthreads();
    const float* ap = eo + ((size_t)b*CE + c0 + lk)*PP + p0 + lm;
    float4 av0 = *(const float4*)ap;
    float4 av1 = *(const float4*)(ap + 4);
    As[lk][lm+0]=av0.x; As[lk][lm+1]=av0.y; As[lk][lm+2]=av0.z; As[lk][lm+3]=av0.w;
    As[lk][lm+4]=av1.x; As[lk][lm+5]=av1.y; As[lk][lm+6]=av1.z; As[lk][lm+7]=av1.w;
    const float* bp = W + (size_t)(a0 + ln)*CE + c0 + lkb;
    float4 bw0 = *(const float4*)bp;
    float4 bw1 = *(const float4*)(bp + 4);
    Bs[lkb+0][ln]=bw0.x; Bs[lkb+1][ln]=bw0.y; Bs[lkb+2][ln]=bw0.z; Bs[lkb+3][ln]=bw0.w;
    Bs[lkb+4][ln]=bw1.x; Bs[lkb+5][ln]=bw1.y; Bs[lkb+6][ln]=bw1.z; Bs[lkb+7][ln]=bw1.w;
    __syncthreads();
    #pragma unroll
    for (int k = 0; k < 16; k++){
      float4 a0v = *(const float4*)&As[k][ty*8];
      float4 a1v = *(const float4*)&As[k][ty*8 + 4];
      float4 b0v = *(const float4*)&Bs[k][tx*8];
      float4 b1v = *(const float4*)&Bs[k][tx*8 + 4];
      float a[8]  = {a0v.x,a0v.y,a0v.z,a0v.w,a1v.x,a1v.y,a1v.z,a1v.w};
      float bb[8] = {b0v.x,b0v.y,b0v.z,b0v.w,b1v.x,b1v.y,b1v.z,b1v.w};
      #pragma unroll
      for (int i2 = 0; i2 < 8; i2++)
        #pragma unroll
        for (int j2 = 0; j2 < 8; j2++)
          acc[i2][j2] = fmaf(a[i2], bb[j2], acc[i2][j2]);
    }
  }
  float bv[8];
  #pragma unroll
  for (int j2 = 0; j2 < 8; j2++) bv[j2] = bias[a0 + tx*8 + j2];
  #pragma unroll
  for (int i2 = 0; i2 < 8; i2++){
    int p = p0 + ty*8 + i2;
    u16x8 o;
    #pragma unroll
    for (int j2 = 0; j2 < 8; j2++) o.v[j2] = f2bf(acc[i2][j2] + bv[j2]);
    *(u16x8*)(att1 + ((size_t)(b*PP + p))*CA + a0 + tx*8) = o;
  }
}

// ---------------- per-step kernels ----------------

// k_pre: blocks 0..31 -> att2slab GEMM  h[64x512] @ [Wd;Wb]^T, K split in 2
//        blocks 32..127 -> gates chunks {0,3,4} into gslab (as before)
__global__ __launch_bounds__(256) void k_pre(
    const float* __restrict__ h, const float* __restrict__ eseq,
    const float* __restrict__ Wda, const float* __restrict__ Wbe,
    const float* __restrict__ Wih, const float* __restrict__ Whh,
    float* __restrict__ att2slab, float* __restrict__ gslab, int t){
  __shared__ float As[16][68];
  __shared__ float Bs[16][68];
  int blk = blockIdx.x, tid = threadIdx.x;
  int ty = tid >> 4, tx = tid & 15;
  int lb  = tid >> 2;
  int lk4 = (tid & 3) * 4;
  int ln  = tid >> 2;
  int lkb = (tid & 3) * 4;
  if (blk < 32){
    // att2 GEMM: out tile = 64 b x 64 n, K window of 256
    int jblk = blk & 15, kc = blk >> 4;
    int n0 = jblk * 64;
    const float* W = (n0 < 512) ? Wda : Wbe;
    int rowbase = (n0 < 512) ? n0 : (n0 - 512);
    float acc[4][4] = {};
    for (int k0 = 0; k0 < 256; k0 += 16){
      __syncthreads();
      float4 q = *(const float4*)(h + (size_t)lb*CD + kc*256 + k0 + lk4);
      As[lk4+0][lb] = q.x; As[lk4+1][lb] = q.y; As[lk4+2][lb] = q.z; As[lk4+3][lb] = q.w;
      float4 w4 = *(const float4*)(W + (size_t)(rowbase + ln)*CD + kc*256 + k0 + lkb);
      Bs[lkb+0][ln] = w4.x; Bs[lkb+1][ln] = w4.y; Bs[lkb+2][ln] = w4.z; Bs[lkb+3][ln] = w4.w;
      __syncthreads();
      #pragma unroll
      for (int k = 0; k < 16; k++){
        float4 av = *(const float4*)&As[k][ty*4];
        float4 bv = *(const float4*)&Bs[k][tx*4];
        float a[4] = {av.x, av.y, av.z, av.w};
        float bq[4] = {bv.x, bv.y, bv.z, bv.w};
        #pragma unroll
        for (int i2 = 0; i2 < 4; i2++)
          #pragma unroll
          for (int j2 = 0; j2 < 4; j2++)
            acc[i2][j2] = fmaf(a[i2], bq[j2], acc[i2][j2]);
      }
    }
    #pragma unroll
    for (int i2 = 0; i2 < 4; i2++){
      int bq = ty*4 + i2;
      float4 o = make_float4(acc[i2][0], acc[i2][1], acc[i2][2], acc[i2][3]);
      *(float4*)(att2slab + ((size_t)(kc*BB + bq))*1024 + n0 + tx*4) = o;
    }
  } else {
    int local = blk - 32;                         // 0..95
    int chunk = (local < 32) ? 0 : ((local < 64) ? 3 : 4);
    int jblk = local & 31;
    int j0 = jblk * 64;
    const float* Wbase; int wrow, wcol0;
    if (chunk == 0){ Wbase = Wih; wrow = 768; wcol0 = 0; }
    else           { Wbase = Whh; wrow = 512; wcol0 = (chunk - 3) * 256; }
    float acc[4][4] = {};
    for (int k0 = 0; k0 < 256; k0 += 16){
      __syncthreads();
      const float* src;
      if (chunk == 0) src = eseq + ((size_t)lb*TT + t)*CEMB;
      else            src = h    + (size_t)lb*CD + (chunk - 3)*256;
      float4 q = *(const float4*)(src + k0 + lk4);
      As[lk4+0][lb] = q.x; As[lk4+1][lb] = q.y; As[lk4+2][lb] = q.z; As[lk4+3][lb] = q.w;
      float4 w4 = *(const float4*)(Wbase + (size_t)(j0 + ln)*wrow + wcol0 + k0 + lkb);
      Bs[lkb+0][ln] = w4.x; Bs[lkb+1][ln] = w4.y; Bs[lkb+2][ln] = w4.z; Bs[lkb+3][ln] = w4.w;
      __syncthreads();
      #pragma unroll
      for (int k = 0; k < 16; k++){
        float4 av = *(const float4*)&As[k][ty*4];
        float4 bv = *(const float4*)&Bs[k][tx*4];
        float a[4] = {av.x, av.y, av.z, av.w};
        float bq[4] = {bv.x, bv.y, bv.z, bv.w};
        #pragma unroll
        for (int i2 = 0; i2 < 4; i2++)
          #pragma unroll
          for (int j2 = 0; j2 < 4; j2++)
            acc[i2][j2] = fmaf(a[i2], bq[j2], acc[i2][j2]);
      }
    }
    #pragma unroll
    for (int i2 = 0; i2 < 4; i2++){
      int bq = ty*4 + i2;
      float4 o = make_float4(acc[i2][0], acc[i2][1], acc[i2][2], acc[i2][3]);
      *(float4*)(gslab + ((size_t)chunk*BB + bq)*G4 + j0 + tx*4) = o;
    }
  }
}

// k_attsm: per-b block. combine att2 slab + biases, e, softmax, awe (via eoT).
__global__ __launch_bounds__(256) void k_attsm(
    const float* __restrict__ att2slab,
    const float* __restrict__ bd, const float* __restrict__ bb_,
    const float* __restrict__ wfull, const float* __restrict__ bfull,
    const u16* __restrict__ att1, const float* __restrict__ eoT,
    float* __restrict__ awe){
  __shared__ float att2s[CA];
  __shared__ float gs[CE];
  __shared__ float wl[CA];
  __shared__ float es[PP];
  __shared__ float red[8];
  int b = blockIdx.x, tid = threadIdx.x;
  wl[tid]       = wfull[tid];
  wl[tid + 256] = wfull[256 + tid];
  {
    const float* s0 = att2slab + (size_t)b*1024;
    const float* s1 = att2slab + (size_t)(BB + b)*1024;
    att2s[tid]       = s0[tid]       + s1[tid]       + bd[tid];
    att2s[tid + 256] = s0[tid + 256] + s1[tid + 256] + bd[tid + 256];
    float2 g0 = *(const float2*)(s0 + 512 + 2*tid);
    float2 g1 = *(const float2*)(s1 + 512 + 2*tid);
    float2 bbv = *(const float2*)(bb_ + 2*tid);
    gs[2*tid]     = sigm(g0.x + g1.x + bbv.x);
    gs[2*tid + 1] = sigm(g0.y + g1.y + bbv.y);
  }
  __syncthreads();
  float e;
  {
    const u16x8* ar = (const u16x8*)(att1 + ((size_t)(b*PP + tid))*CA);
    float s = 0.f;
    for (int k8 = 0; k8 < CA/8; k8++){
      u16x8 a8 = ar[k8];
      #pragma unroll
      for (int q = 0; q < 8; q++){
        float v = bf2f(a8.v[q]) + att2s[k8*8 + q];
        s = fmaf(fmaxf(v, 0.f), wl[k8*8 + q], s);
      }
    }
    e = s + bfull[0];
  }
  int lane = tid & 63, wid = tid >> 6;
  float v = e;
  #pragma unroll
  for (int off = 32; off; off >>= 1) v = fmaxf(v, __shfl_xor(v, off, 64));
  if (lane == 0) red[wid] = v;
  __syncthreads();
  float mx = fmaxf(fmaxf(red[0], red[1]), fmaxf(red[2], red[3]));
  float ex = __expf(e - mx);
  float sm = ex;
  #pragma unroll
  for (int off = 32; off; off >>= 1) sm += __shfl_xor(sm, off, 64);
  if (lane == 0) red[4 + wid] = sm;
  __syncthreads();
  float tot = red[4] + red[5] + red[6] + red[7];
  es[tid] = ex / tot;
  __syncthreads();
  {
    // awe[b][c] = gate[c] * sum_p eoT[b][p][c] * alpha[p]; thread owns c=2*tid, 2*tid+1
    const float* base = eoT + (size_t)b*PP*CE + 2*tid;
    float s0 = 0.f, s1 = 0.f;
    #pragma unroll 4
    for (int p = 0; p < PP; p++){
      float2 v2 = *(const float2*)(base + (size_t)p*CE);
      float a = es[p];
      s0 = fmaf(v2.x, a, s0);
      s1 = fmaf(v2.y, a, s1);
    }
    float2 o = make_float2(s0 * gs[2*tid], s1 * gs[2*tid + 1]);
    *(float2*)(awe + b*CE + 2*tid) = o;
  }
}

// k_gl: gates chunks {1,2} (awe @ Wih[:,256:768], full K=512) + slab{0,3,4} + LSTM.
// block -> 4 d-values (d0 = blk*4); thread (bq = tid&63, cq = tid>>6) owns (b=bq, d=d0+cq),
// computing all four gates i,f,g,o for that cell.
__global__ __launch_bounds__(256) void k_gl(
    const float* __restrict__ awe, const float* __restrict__ Wih,
    const float* __restrict__ gslab,
    const float* __restrict__ bih, const float* __restrict__ bhh,
    float* __restrict__ h, float* __restrict__ c,
    float* __restrict__ h_all, int t){
  __shared__ float awe_s[16][68];
  __shared__ float W_s[16][20];
  int blk = blockIdx.x, tid = threadIdx.x;
  int d0 = blk * 4;
  int bq = tid & 63, cq = tid >> 6;     // d = d0 + cq
  int lb  = tid >> 2;
  int lk4 = (tid & 3) * 4;
  float4 acc = make_float4(0.f, 0.f, 0.f, 0.f);  // (i,f,g,o) for (bq, d0+cq)
  for (int k0 = 0; k0 < 512; k0 += 16){
    __syncthreads();
    float4 q = *(const float4*)(awe + (size_t)lb*CE + k0 + lk4);
    awe_s[lk4+0][lb] = q.x; awe_s[lk4+1][lb] = q.y;
    awe_s[lk4+2][lb] = q.z; awe_s[lk4+3][lb] = q.w;
    if (tid < 64){
      int ln = tid >> 2;                 // c_loc = i*4 + g
      int gi2 = ln & 3, di2 = ln >> 2;   // gate, d-offset
      int grow = gi2*512 + d0 + di2;
      float4 w4 = *(const float4*)(Wih + (size_t)grow*768 + 256 + k0 + lk4);
      W_s[lk4+0][ln] = w4.x; W_s[lk4+1][ln] = w4.y;
      W_s[lk4+2][ln] = w4.z; W_s[lk4+3][ln] = w4.w;
    }
    __syncthreads();
    #pragma unroll
    for (int k = 0; k < 16; k++){
      float a = awe_s[k][bq];
      float4 w = *(const float4*)&W_s[k][cq*4];
      acc.x = fmaf(a, w.x, acc.x);
      acc.y = fmaf(a, w.y, acc.y);
      acc.z = fmaf(a, w.z, acc.z);
      acc.w = fmaf(a, w.w, acc.w);
    }
  }
  int d = d0 + cq;
  float gi = acc.x + bih[d]        + bhh[d];
  float gf = acc.y + bih[d + 512]  + bhh[d + 512];
  float gg = acc.z + bih[d + 1024] + bhh[d + 1024];
  float go = acc.w + bih[d + 1536] + bhh[d + 1536];
  #pragma unroll
  for (int s = 0; s < 5; s += 1){
    if (s == 1 || s == 2) continue;     // chunks 1,2 computed here
    const float* base = gslab + ((size_t)s*BB + bq)*G4;
    gi += base[d]; gf += base[d + 512]; gg += base[d + 1024]; go += base[d + 1536];
  }
  int i = bq*CD + d;
  float cn = sigm(gf)*c[i] + sigm(gi)*tanhf(gg);
  float hn = sigm(go)*tanhf(cn);
  c[i] = cn; h[i] = hn;
  h_all[((size_t)bq*TT + t)*CD + d] = hn;
}

// ---------------- final big GEMM, fp32 output ----------------
__global__ __launch_bounds__(256) void k_pred(
    const float* __restrict__ h_all, const float* __restrict__ Wfc,
    const float* __restrict__ bfc, const int* __restrict__ lens,
    const int* __restrict__ flag, float* __restrict__ out){
  __shared__ float As[16][132];
  __shared__ float Bs[16][132];
  int n0 = blockIdx.x * 128;
  int m0 = blockIdx.y * 128;
  int tid = threadIdx.x;
  int ty = tid >> 4, tx = tid & 15;
  float acc[8][8] = {};
  int lm  = tid >> 1;
  int lkb = (tid & 1) * 8;
  for (int c0 = 0; c0 < CD; c0 += 16){
    __syncthreads();
    int m = m0 + lm;
    float4 a0v, a1v;
    if (m < BB*TT){
      a0v = *(const float4*)(h_all + (size_t)m*CD + c0 + lkb);
      a1v = *(const float4*)(h_all + (size_t)m*CD + c0 + lkb + 4);
    } else {
      a0v = make_float4(0.f,0.f,0.f,0.f); a1v = a0v;
    }
    As[lkb+0][lm] = a0v.x; As[lkb+1][lm] = a0v.y; As[lkb+2][lm] = a0v.z; As[lkb+3][lm] = a0v.w;
    As[lkb+4][lm] = a1v.x; As[lkb+5][lm] = a1v.y; As[lkb+6][lm] = a1v.z; As[lkb+7][lm] = a1v.w;
    const float* bp = Wfc + (size_t)(n0 + lm)*CD + c0 + lkb;
    float4 b0v = *(const float4*)bp;
    float4 b1v = *(const float4*)(bp + 4);
    Bs[lkb+0][lm] = b0v.x; Bs[lkb+1][lm] = b0v.y; Bs[lkb+2][lm] = b0v.z; Bs[lkb+3][lm] = b0v.w;
    Bs[lkb+4][lm] = b1v.x; Bs[lkb+5][lm] = b1v.y; Bs[lkb+6][lm] = b1v.z; Bs[lkb+7][lm] = b1v.w;
    __syncthreads();
    #pragma unroll
    for (int k = 0; k < 16; k++){
      float4 av0 = *(const float4*)&As[k][ty*8];
      float4 av1 = *(const float4*)&As[k][ty*8 + 4];
      float4 bv0 = *(const float4*)&Bs[k][tx*8];
      float4 bv1 = *(const float4*)&Bs[k][tx*8 + 4];
      float a[8]  = {av0.x,av0.y,av0.z,av0.w,av1.x,av1.y,av1.z,av1.w};
      float bb[8] = {bv0.x,bv0.y,bv0.z,bv0.w,bv1.x,bv1.y,bv1.z,bv1.w};
      #pragma unroll
      for (int i2 = 0; i2 < 8; i2++)
        #pragma unroll
        for (int j2 = 0; j2 < 8; j2++)
          acc[i2][j2] = fmaf(a[i2], bb[j2], acc[i2][j2]);
    }
  }
  float bv[8];
  #pragma unroll
  for (int j2 = 0; j2 < 8; j2++) bv[j2] = bfc[n0 + tx*8 + j2];
  int f = flag[0];
  #pragma unroll
  for (int i2 = 0; i2 < 8; i2++){
    int m = m0 + ty*8 + i2;
    if (m < BB*TT){
      int b = m / TT, t = m - b*TT;
      int lb = f ? lens[2*b] : lens[b];
      bool active = (t < lb - 1);
      float4 o0, o1;
      if (active){
        o0 = make_float4(acc[i2][0]+bv[0], acc[i2][1]+bv[1], acc[i2][2]+bv[2], acc[i2][3]+bv[3]);
        o1 = make_float4(acc[i2][4]+bv[4], acc[i2][5]+bv[5], acc[i2][6]+bv[6], acc[i2][7]+bv[7]);
      } else {
        o0 = make_float4(0.f,0.f,0.f,0.f); o1 = o0;
      }
      float* op = out + (size_t)m*VV + n0 + tx*8;
      *(float4*)op       = o0;
      *(float4*)(op + 4) = o1;
    }
  }
}

extern "C" void kernel_launch(void* const* d_in, const int* in_sizes, int n_in,
                              void* d_out, int out_size, void* d_ws, size_t ws_size,
                              hipStream_t stream){
  const float* eo    = (const float*)d_in[0];
  const int*   caps  = (const int*)d_in[1];
  const int*   lens  = (const int*)d_in[2];
  const float* Wea   = (const float*)d_in[3];
  const float* bea   = (const float*)d_in[4];
  const float* Wda   = (const float*)d_in[5];
  const float* bda   = (const float*)d_in[6];
  const float* wfull = (const float*)d_in[7];
  const float* bfull = (const float*)d_in[8];
  const float* emb   = (const float*)d_in[9];
  const float* Wih   = (const float*)d_in[10];
  const float* Whh   = (const float*)d_in[11];
  const float* bih   = (const float*)d_in[12];
  const float* bhh   = (const float*)d_in[13];
  const float* Wirh  = (const float*)d_in[14];
  const float* birh  = (const float*)d_in[15];
  const float* Wirc  = (const float*)d_in[16];
  const float* birc  = (const float*)d_in[17];
  const float* Wbe   = (const float*)d_in[18];
  const float* bbe   = (const float*)d_in[19];
  const float* Wfc   = (const float*)d_in[20];
  const float* bfc   = (const float*)d_in[21];
  float* out = (float*)d_out;

  // scratch that dies before k_pred lives in the head of d_out (127 MB fp32);
  // k_pred overwrites every byte of d_out afterwards (stream-ordered).
  char* ob = (char*)d_out;
  u16*   att1     = (u16*)(ob + 0);           // 16,777,216 B
  float* gslab    = (float*)(ob + 16777216);  //  2,621,440 B (slots 0,3,4 used)
  float* eseq     = (float*)(ob + 19398656);  //  2,031,616 B
  float* mean_enc = (float*)(ob + 21430272);  //    131,072 B
  float* awe      = (float*)(ob + 21561344);  //    131,072 B
  float* hbuf     = (float*)(ob + 21692416);  //    131,072 B
  float* cbuf     = (float*)(ob + 21823488);  //    131,072 B
  float* att2slab = (float*)(ob + 21954560);  //    524,288 B  (2 x 64 x 1024)
  float* eoT      = (float*)(ob + 22478848);  // 33,554,432 B  (end ~56 MB << 127 MB)
  char* w = (char*)d_ws;
  float* h_all    = (float*)w;                //  4,063,232 B
  int*   iflag    = (int*)(w + 4063232);

  k_detect<<<1, 64, 0, stream>>>(lens, iflag);
  k_mean<<<128, 256, 0, stream>>>(eo, mean_enc);
  k_trans<<<dim3(8, 4, BB), 256, 0, stream>>>(eo, eoT);
  k_emb <<<496, 256, 0, stream>>>(caps, emb, eseq, iflag);
  k_init<<<128, 256, 0, stream>>>(mean_enc, Wirh, birh, Wirc, birc, hbuf, cbuf);
  k_att1<<<dim3(4, 2, BB), 256, 0, stream>>>(eo, Wea, bea, att1);
  for (int t = 0; t < TT; t++){
    k_pre  <<<128, 256, 0, stream>>>(hbuf, eseq, Wda, Wbe, Wih, Whh, att2slab, gslab, t);
    k_attsm<<<BB, 256, 0, stream>>>(att2slab, bda, bbe, wfull, bfull, att1, eoT, awe);
    k_gl   <<<128, 256, 0, stream>>>(awe, Wih, gslab, bih, bhh, hbuf, cbuf, h_all, t);
  }
  k_pred<<<dim3(125, 16), 256, 0, stream>>>(h_all, Wfc, bfc, lens, iflag, out);
}